// Round 16
// baseline (89.101 us; speedup 1.0000x reference)
//
#include <hip/hip_runtime.h>
#include <hip/hip_bf16.h>

#define N_NODES 65536
#define N_EDGES (N_NODES * 7)
#define NSEG    (N_NODES * 7)          // 458752
#define CAP     12
#define ZROW    65536                  // index of the all-zero row in xb

typedef short short8 __attribute__((ext_vector_type(8)));
typedef float f32x4  __attribute__((ext_vector_type(4)));

// async global->LDS, 16B per lane; LDS dst is wave-uniform base + lane*16
#define GLDS(g, l) __builtin_amdgcn_global_load_lds(                        \
    (const __attribute__((address_space(1))) void*)(g),                    \
    (__attribute__((address_space(3))) void*)(l), 16, 0, 0)

// f32 -> bf16 via hardware cvt (compiler emits v_cvt_pk_bf16_f32 for pairs)
__device__ __forceinline__ unsigned short f2bf(float f) {
    return __builtin_bit_cast(unsigned short, (__bf16)f);
}
__device__ __forceinline__ unsigned pack2(float lo, float hi) {
    return (unsigned)f2bf(lo) | ((unsigned)f2bf(hi) << 16);
}
// bf16 pair unpack from dword
__device__ __forceinline__ float bflo(unsigned d) { return __uint_as_float(d << 16); }
__device__ __forceinline__ float bfhi(unsigned d) { return __uint_as_float(d & 0xffff0000u); }

// ---------------- fused prep: edge scatter + x->bf16 + W->B-frag ----------------
// seg32[seg] = cnt(7b at bit 0) | typecount_u(5b at bit 7+5u). Pre-zeroed by memset.
__global__ __launch_bounds__(256) void k_big(const float* __restrict__ x,
                                             const int* __restrict__ eidx,
                                             const int* __restrict__ etype,
                                             const int* __restrict__ ntype,
                                             const float* __restrict__ W,
                                             unsigned short* __restrict__ xb,
                                             unsigned short* __restrict__ wb,
                                             unsigned* __restrict__ seg32,
                                             unsigned short* __restrict__ scol) {
    int i = blockIdx.x * 256 + threadIdx.x;     // grid 4096*256 = 1048576

    // edge scatter (issue first: its random loads overlap the streaming below)
    if (i < N_EDGES) {
        int t = etype[i];
        if (t < 6) {                    // type-6 slot overwritten by self-loop
            int r = eidx[i];
            int c = eidx[N_EDGES + i];
            int u = ntype[c];
            unsigned seg = (unsigned)r * 7u + (unsigned)t;
            unsigned inc = 1u | (1u << (7 + 5 * u));
            unsigned old = atomicAdd(&seg32[seg], inc);
            unsigned slot = old & 0x7fu;
            if (slot < CAP) scol[seg * CAP + slot] = (unsigned short)c;
        }
    }

    // x -> bf16 rows
    {
        int row = i >> 4, mm = i & 15;
        const f32x4* p = reinterpret_cast<const f32x4*>(x + (size_t)row * 128 + mm * 8);
        f32x4 v0 = p[0], v1 = p[1];
        uint4 w;
        w.x = pack2(v0[0], v0[1]); w.y = pack2(v0[2], v0[3]);
        w.z = pack2(v1[0], v1[1]); w.w = pack2(v1[2], v1[3]);
        reinterpret_cast<uint4*>(xb)[i] = w;
    }

    // zero row (gather fallback target)
    if (i < 16) reinterpret_cast<uint4*>(xb + (size_t)ZROW * 128)[i] = (uint4){0u, 0u, 0u, 0u};

    // W -> bf16 B-fragment order (16x16x32): wb[(((t*5+kc)*8+cb)*64+lane)*8+j]
    if (i < 143360) {
        int j    = i & 7;
        int lane = (i >> 3) & 63;
        int cb   = (i >> 9) & 7;
        int tkc  = i >> 12;
        int kc   = tkc % 5;
        int t    = tkc / 5;
        int k = kc * 32 + ((lane >> 4) << 3) + j;
        int c = cb * 16 + (lane & 15);
        float v = (k < 133) ? W[(t * 133 + k) * 128 + c] : 0.0f;
        wb[i] = f2bf(v);
    }
}

// ---------------- main fused kernel: DMA-gathered tiles, 2 barriers ----------------
// 512 threads, 32 rows/block. Phase A: global_load_lds stages e0 of ALL 7 tiles
// (per-lane random global src = the gather itself; pre-swizzled source chunk
// m^(r&7) keeps LDS linear, rule #21) + branchless e0/e1 reg loads. Barrier 1
// (drains vmcnt). Phase B: cnt>=2 rows overwrite with true mean; one-hots.
// Barrier 2. Phase C: 70-MFMA marathon (wave = cb, 2 strips), B double-buffered.
// One latency exposure for the whole gather; zero regs held across marathons.
__global__ __launch_bounds__(512, 4) void k_main(const unsigned short* __restrict__ xb,
                                                 const int* __restrict__ ntype,
                                                 const unsigned* __restrict__ seg32,
                                                 const unsigned short* __restrict__ scol,
                                                 const unsigned short* __restrict__ wb,
                                                 float* __restrict__ out) {
    __shared__ unsigned short sAd[7 * 32 * 128];  // 57344 B, swizzled 16B chunks
    __shared__ unsigned short oh [7 * 32 * 32];   // 14336 B, channels 128..159

    const int tid  = threadIdx.x;
    const int lane = tid & 63;
    const int wid  = tid >> 6;
    const int n0   = blockIdx.x * 32;
    const int r    = tid >> 4;          // row 0..31  (= 4*wid + (lane>>4))
    const int m    = tid & 15;          // 16B chunk 0..15
    const int n    = n0 + r;
    const int swz  = r & 7;

    // zero the one-hot array (channels 133..159 stay zero)
    {
        unsigned* zp = reinterpret_cast<unsigned*>(oh);
        #pragma unroll
        for (int i = 0; i < 7; ++i) zp[tid + i * 512] = 0u;
    }

    // descriptors (16 lanes/row share addr -> L1 broadcast)
    unsigned sv[6]; uint2 q2[6];
    #pragma unroll
    for (int t = 0; t < 6; ++t) {
        sv[t] = seg32[n * 7 + t];
        q2[t] = *reinterpret_cast<const uint2*>(scol + ((size_t)n * 7 + t) * CAP);
    }
    const int ntS = ntype[n];

    // ---- phase A1: DMA e0 of all 7 tiles (source chunk pre-swizzled) ----
    const int gch = (m ^ swz) << 3;     // source chunk offset in shorts
    #pragma unroll
    for (int t = 0; t < 7; ++t) {
        unsigned c0;
        if (t < 6) {
            unsigned cnt = sv[t] & 0x7fu;
            c0 = (cnt >= 1u) ? (q2[t].x & 0xffffu) : (unsigned)ZROW;
        } else {
            c0 = (unsigned)n;           // self-loop slot
        }
        GLDS(xb + (size_t)c0 * 128 + gch, sAd + t * 4096 + wid * 512);
    }

    // ---- phase A2: branchless e0/e1 register loads (for cnt>=2 corrections) ----
    uint4 rA[6], rB[6];
    #pragma unroll
    for (int t = 0; t < 6; ++t) {
        unsigned cnt = sv[t] & 0x7fu;
        unsigned c0 = (cnt >= 1u) ? (q2[t].x & 0xffffu) : (unsigned)ZROW;
        unsigned c1 = (cnt >= 2u) ? (q2[t].x >> 16)     : (unsigned)ZROW;
        rA[t] = *reinterpret_cast<const uint4*>(xb + (size_t)c0 * 128 + m * 8);
        rB[t] = *reinterpret_cast<const uint4*>(xb + (size_t)c1 * 128 + m * 8);
    }

    __syncthreads();    // vmcnt(0): DMA tiles valid in LDS, reg loads complete

    // ---- phase B: corrections (cnt>=2) + one-hot writes ----
    #pragma unroll
    for (int t = 0; t < 6; ++t) {
        const unsigned cnt = sv[t] & 0x7fu;
        const float inv = (cnt > 1u) ? __builtin_amdgcn_rcpf((float)cnt) : 1.0f;
        if (cnt >= 2u) {
            uint4 a0 = rA[t], b0 = rB[t];
            float f[8];
            f[0] = bflo(a0.x) + bflo(b0.x); f[1] = bfhi(a0.x) + bfhi(b0.x);
            f[2] = bflo(a0.y) + bflo(b0.y); f[3] = bfhi(a0.y) + bfhi(b0.y);
            f[4] = bflo(a0.z) + bflo(b0.z); f[5] = bfhi(a0.z) + bfhi(b0.z);
            f[6] = bflo(a0.w) + bflo(b0.w); f[7] = bfhi(a0.w) + bfhi(b0.w);
            const unsigned ce = (cnt < (unsigned)CAP) ? cnt : (unsigned)CAP;
            const size_t segbase = ((size_t)n * 7 + t) * CAP;
            for (unsigned e = 2; e < ce; ++e) {
                unsigned c = scol[segbase + e];
                uint4 v = *reinterpret_cast<const uint4*>(xb + (size_t)c * 128 + m * 8);
                f[0] += bflo(v.x); f[1] += bfhi(v.x);
                f[2] += bflo(v.y); f[3] += bfhi(v.y);
                f[4] += bflo(v.z); f[5] += bfhi(v.z);
                f[6] += bflo(v.w); f[7] += bfhi(v.w);
            }
            uint4 w;
            w.x = pack2(f[0] * inv, f[1] * inv);
            w.y = pack2(f[2] * inv, f[3] * inv);
            w.z = pack2(f[4] * inv, f[5] * inv);
            w.w = pack2(f[6] * inv, f[7] * inv);
            *reinterpret_cast<uint4*>(sAd + (t * 32 + r) * 128 + gch) = w;
        }
        if (m == 0) {
            float g0 = (float)((sv[t] >> 7)  & 31u) * inv;
            float g1 = (float)((sv[t] >> 12) & 31u) * inv;
            float g2 = (float)((sv[t] >> 17) & 31u) * inv;
            float g3 = (float)((sv[t] >> 22) & 31u) * inv;
            float g4 = (float)((sv[t] >> 27) & 31u) * inv;
            uint4 wo;
            wo.x = pack2(g0, g1); wo.y = pack2(g2, g3);
            wo.z = pack2(g4, 0.f); wo.w = 0u;
            *reinterpret_cast<uint4*>(oh + (t * 32 + r) * 32) = wo;
        }
    }
    if (m == 0) {       // t=6 one-hot: own node type
        uint4 wo;
        wo.x = pack2((float)(ntS == 0), (float)(ntS == 1));
        wo.y = pack2((float)(ntS == 2), (float)(ntS == 3));
        wo.z = pack2((float)(ntS == 4), 0.f);
        wo.w = 0u;
        *reinterpret_cast<uint4*>(oh + (6 * 32 + r) * 32) = wo;
    }

    __syncthreads();

    // ---- phase C: MFMA marathon (wave = cb wid; strips 0,1; B dbl-buffered) ----
    const int arl = lane & 15;
    const int g8  = (lane >> 4) << 3;
    const int sgh = g8 >> 3;            // 16B-chunk sub-index 0..3
    const int rs  = arl & 7;            // read-side swizzle (rows 16 apart share it)
    f32x4 acc0 = {0.f, 0.f, 0.f, 0.f};
    f32x4 acc1 = {0.f, 0.f, 0.f, 0.f};

    short8 bv[2][5];
    #pragma unroll
    for (int kc = 0; kc < 5; ++kc)
        bv[0][kc] = *reinterpret_cast<const short8*>(
            wb + (((kc * 8 + wid) << 6) + lane) * 8);

    #pragma unroll
    for (int t = 0; t < 7; ++t) {
        const int cur = t & 1, nxt = cur ^ 1;
        if (t < 6) {
            #pragma unroll
            for (int kc = 0; kc < 5; ++kc)
                bv[nxt][kc] = *reinterpret_cast<const short8*>(
                    wb + (((((t + 1) * 5 + kc) * 8 + wid) << 6) + lane) * 8);
        }
        #pragma unroll
        for (int kc = 0; kc < 4; ++kc) {
            const int so = ((kc * 4 + sgh) ^ rs) << 3;
            short8 a0 = *reinterpret_cast<const short8*>(
                sAd + (t * 32 + arl) * 128 + so);
            short8 a1 = *reinterpret_cast<const short8*>(
                sAd + (t * 32 + 16 + arl) * 128 + so);
            acc0 = __builtin_amdgcn_mfma_f32_16x16x32_bf16(a0, bv[cur][kc], acc0, 0, 0, 0);
            acc1 = __builtin_amdgcn_mfma_f32_16x16x32_bf16(a1, bv[cur][kc], acc1, 0, 0, 0);
        }
        {   // kc = 4: one-hot chunk (channels 128..159)
            short8 a0 = *reinterpret_cast<const short8*>(
                oh + (t * 32 + arl) * 32 + g8);
            short8 a1 = *reinterpret_cast<const short8*>(
                oh + (t * 32 + 16 + arl) * 32 + g8);
            acc0 = __builtin_amdgcn_mfma_f32_16x16x32_bf16(a0, bv[cur][4], acc0, 0, 0, 0);
            acc1 = __builtin_amdgcn_mfma_f32_16x16x32_bf16(a1, bv[cur][4], acc1, 0, 0, 0);
        }
    }

    // epilogue: C/D layout col = lane&15, row = (lane>>4)*4 + reg
    const int orow = n0 + ((lane >> 4) << 2);
    const int ocol = (wid << 4) + (lane & 15);
    #pragma unroll
    for (int rr = 0; rr < 4; ++rr) {
        out[(size_t)(orow + rr) * 128 + ocol]      = acc0[rr];
        out[(size_t)(orow + 16 + rr) * 128 + ocol] = acc1[rr];
    }
}

// ---------------- launch ----------------

extern "C" void kernel_launch(void* const* d_in, const int* in_sizes, int n_in,
                              void* d_out, int out_size, void* d_ws, size_t ws_size,
                              hipStream_t stream) {
    const float* x     = (const float*)d_in[0];
    const int*   eidx  = (const int*)d_in[1];
    const int*   etype = (const int*)d_in[2];
    const int*   ntype = (const int*)d_in[3];
    const float* W     = (const float*)d_in[4];
    float* out = (float*)d_out;

    // ws: xb (65537 rows) 16777472 | wb 286720 | seg32 1835008 | scol 11010048
    unsigned short* xb    = (unsigned short*)d_ws;
    unsigned short* wb    = (unsigned short*)((char*)d_ws + 16777472);
    unsigned*       seg32 = (unsigned*)((char*)d_ws + 17064192);
    unsigned short* scol  = (unsigned short*)((char*)d_ws + 18899200);

    hipMemsetAsync(seg32, 0, NSEG * sizeof(unsigned), stream);
    k_big <<<4096,         256, 0, stream>>>(x, eidx, etype, ntype, W, xb, wb, seg32, scol);
    k_main<<<N_NODES / 32, 512, 0, stream>>>(xb, ntype, seg32, scol, wb, out);
}

// Round 17
// 79.530 us; speedup vs baseline: 1.1203x; 1.1203x over previous
//
#include <hip/hip_runtime.h>
#include <hip/hip_bf16.h>

#define N_NODES 65536
#define N_EDGES (N_NODES * 7)
#define NSEG    (N_NODES * 7)          // 458752
#define CAP     12
#define ZROW    65536                  // index of the all-zero row in xb

typedef short short8 __attribute__((ext_vector_type(8)));
typedef float f32x4  __attribute__((ext_vector_type(4)));

// f32 -> bf16 via hardware cvt (compiler emits v_cvt_pk_bf16_f32 for pairs)
__device__ __forceinline__ unsigned short f2bf(float f) {
    return __builtin_bit_cast(unsigned short, (__bf16)f);
}
__device__ __forceinline__ unsigned pack2(float lo, float hi) {
    return (unsigned)f2bf(lo) | ((unsigned)f2bf(hi) << 16);
}
// bf16 pair unpack from dword
__device__ __forceinline__ float bflo(unsigned d) { return __uint_as_float(d << 16); }
__device__ __forceinline__ float bfhi(unsigned d) { return __uint_as_float(d & 0xffff0000u); }

// ---------------- role-split prep kernel ----------------
// Blocks 0..1791: edge scatter ONLY (latency-bound, hides among 458K chains);
//   blocks 0..559 additionally convert W (streaming, fills their idle mem slots).
// Blocks 1792..5887: pure streaming x->bf16 conversion at full burst BW.
// (R16 lesson: welding the scatter chain into streaming threads throttled both.)
__global__ __launch_bounds__(256) void k_big(const float* __restrict__ x,
                                             const int* __restrict__ eidx,
                                             const int* __restrict__ etype,
                                             const int* __restrict__ ntype,
                                             const float* __restrict__ W,
                                             unsigned short* __restrict__ xb,
                                             unsigned short* __restrict__ wb,
                                             unsigned* __restrict__ seg32,
                                             unsigned short* __restrict__ scol) {
    const int b = blockIdx.x;
    if (b < 1792) {
        // ---- edge scatter: seg32[seg] = cnt(7b) | typecount_u(5b at 7+5u) ----
        int e = b * 256 + threadIdx.x;          // 0 .. 458751
        int t = etype[e];
        if (t < 6) {                            // type-6 slot overwritten by self-loop
            int r = eidx[e];
            int c = eidx[N_EDGES + e];
            int u = ntype[c];
            unsigned seg = (unsigned)r * 7u + (unsigned)t;
            unsigned inc = 1u | (1u << (7 + 5 * u));
            unsigned old = atomicAdd(&seg32[seg], inc);
            unsigned slot = old & 0x7fu;
            if (slot < CAP) scol[seg * CAP + slot] = (unsigned short)c;
        }
        // ---- W -> bf16 B-fragment order (blocks 0..559) ----
        if (e < 143360) {
            int i = e;
            int j    = i & 7;
            int lane = (i >> 3) & 63;
            int cb   = (i >> 9) & 7;
            int tkc  = i >> 12;
            int kc   = tkc % 5;
            int t2   = tkc / 5;
            int k = kc * 32 + ((lane >> 4) << 3) + j;
            int c = cb * 16 + (lane & 15);
            float v = (k < 133) ? W[(t2 * 133 + k) * 128 + c] : 0.0f;
            wb[i] = f2bf(v);
        }
    } else {
        // ---- streaming x -> bf16 (16 threads/row, 8 floats each) ----
        int i = (b - 1792) * 256 + threadIdx.x;     // 0 .. 1048575
        int row = i >> 4, mm = i & 15;
        const f32x4* p = reinterpret_cast<const f32x4*>(x + (size_t)row * 128 + mm * 8);
        f32x4 v0 = p[0], v1 = p[1];
        uint4 w;
        w.x = pack2(v0[0], v0[1]); w.y = pack2(v0[2], v0[3]);
        w.z = pack2(v1[0], v1[1]); w.w = pack2(v1[2], v1[3]);
        reinterpret_cast<uint4*>(xb)[i] = w;
        if (i < 16) reinterpret_cast<uint4*>(xb + (size_t)ZROW * 128)[i] = (uint4){0u,0u,0u,0u};
    }
}

// ---------------- main fused kernel (R9, proven 49.5 us) ----------------
// Two-phase schedule, sA = 4 tiles (43 KB) -> 3 blocks/CU (24 waves).
// Phase 1: build {t0,t1,t2,self}, barrier, marathon-1 (B types {0,1,2,6}).
// Phase 2: issue t3-5 loads, rebuild slots 0-2, barrier, marathon-2 ({3,4,5}).
// No registers held across marathon-1 (R8 spill lesson).
__global__ __launch_bounds__(512, 6) void k_main(const unsigned short* __restrict__ xb,
                                                 const int* __restrict__ ntype,
                                                 const unsigned* __restrict__ seg32,
                                                 const unsigned short* __restrict__ scol,
                                                 const unsigned short* __restrict__ wb,
                                                 float* __restrict__ out) {
    __shared__ unsigned short sA[4 * 32 * 168];   // 43008 B

    const int tid  = threadIdx.x;
    const int lane = tid & 63;
    const int wid  = tid >> 6;
    const int n0   = blockIdx.x * 32;
    const int r    = tid >> 4;      // row 0..31
    const int m    = tid & 15;      // 8-channel chunk
    const int n    = n0 + r;

    // zero pad: dwords 68..79 of each of the 128 rows (shorts 136..159)
    #pragma unroll
    for (int k2 = 0; k2 < 3; ++k2) {
        int i = tid + k2 * 512;
        int row = i / 12, j = i - row * 12;
        reinterpret_cast<unsigned*>(sA)[row * 84 + 68 + j] = 0u;
    }

    // all per-type packed counters + first-4 edge cols (L1-broadcast in 16-lane group)
    unsigned sv[6], c_t[6];
    uint2 q2[6];
    #pragma unroll
    for (int t = 0; t < 6; ++t) {
        sv[t]  = seg32[n * 7 + t];
        c_t[t] = sv[t] & 0x7fu;
        q2[t]  = *reinterpret_cast<const uint2*>(scol + ((size_t)n * 7 + t) * CAP);
    }

    // ---- tile builder (one (row,t) segment, this thread's 8 channels) ----
    auto build_tile = [&](int t, int tile, short8 xa, short8 xbv) {
        const unsigned cntv = c_t[t];
        const float inv = (cntv > 1u) ? __builtin_amdgcn_rcpf((float)cntv) : 1.0f;
        uint4 a4 = *reinterpret_cast<const uint4*>(&xa);
        uint4 w;
        if (cntv <= 1u) {
            w = a4;                      // cnt=0 -> ZROW zeros; cnt=1 -> exact copy
        } else {
            uint4 b4 = *reinterpret_cast<const uint4*>(&xbv);
            float a[8];
            a[0] = bflo(a4.x) + bflo(b4.x); a[1] = bfhi(a4.x) + bfhi(b4.x);
            a[2] = bflo(a4.y) + bflo(b4.y); a[3] = bfhi(a4.y) + bfhi(b4.y);
            a[4] = bflo(a4.z) + bflo(b4.z); a[5] = bfhi(a4.z) + bfhi(b4.z);
            a[6] = bflo(a4.w) + bflo(b4.w); a[7] = bfhi(a4.w) + bfhi(b4.w);
            if (cntv >= 3u) {            // rare tail (~8% of segments)
                const unsigned ce = (cntv < (unsigned)CAP) ? cntv : (unsigned)CAP;
                {
                    unsigned c2 = q2[t].y & 0xffffu;
                    short8 v = *reinterpret_cast<const short8*>(xb + (size_t)c2 * 128 + m * 8);
                    uint4 v4 = *reinterpret_cast<const uint4*>(&v);
                    a[0] += bflo(v4.x); a[1] += bfhi(v4.x);
                    a[2] += bflo(v4.y); a[3] += bfhi(v4.y);
                    a[4] += bflo(v4.z); a[5] += bfhi(v4.z);
                    a[6] += bflo(v4.w); a[7] += bfhi(v4.w);
                }
                if (ce >= 4u) {
                    unsigned c3 = q2[t].y >> 16;
                    short8 v = *reinterpret_cast<const short8*>(xb + (size_t)c3 * 128 + m * 8);
                    uint4 v4 = *reinterpret_cast<const uint4*>(&v);
                    a[0] += bflo(v4.x); a[1] += bfhi(v4.x);
                    a[2] += bflo(v4.y); a[3] += bfhi(v4.y);
                    a[4] += bflo(v4.z); a[5] += bfhi(v4.z);
                    a[6] += bflo(v4.w); a[7] += bfhi(v4.w);
                    const size_t segbase = ((size_t)n * 7 + t) * CAP;
                    for (unsigned e = 4; e < ce; ++e) {
                        unsigned c = scol[segbase + e];
                        short8 ve = *reinterpret_cast<const short8*>(xb + (size_t)c * 128 + m * 8);
                        uint4 v4e = *reinterpret_cast<const uint4*>(&ve);
                        a[0] += bflo(v4e.x); a[1] += bfhi(v4e.x);
                        a[2] += bflo(v4e.y); a[3] += bfhi(v4e.y);
                        a[4] += bflo(v4e.z); a[5] += bfhi(v4e.z);
                        a[6] += bflo(v4e.w); a[7] += bfhi(v4e.w);
                    }
                }
            }
            w.x = pack2(a[0] * inv, a[1] * inv); w.y = pack2(a[2] * inv, a[3] * inv);
            w.z = pack2(a[4] * inv, a[5] * inv); w.w = pack2(a[6] * inv, a[7] * inv);
        }
        *reinterpret_cast<uint4*>(sA + (tile * 32 + r) * 168 + m * 8) = w;
        if (m < 4) {
            int i0 = 2 * m, i1 = 2 * m + 1;
            float g0 = (i0 < 5) ? (float)((sv[t] >> (7 + 5 * i0)) & 31u) : 0.f;
            float g1 = (i1 < 5) ? (float)((sv[t] >> (7 + 5 * i1)) & 31u) : 0.f;
            reinterpret_cast<unsigned*>(sA)[(tile * 32 + r) * 84 + 64 + m] =
                pack2(g0 * inv, g1 * inv);
        }
    };

    // ---- phase-1: issue t0..2 e0/e1 + self loads, then build ----
    {
        short8 xA[3], xB[3], xS;
        #pragma unroll
        for (int t = 0; t < 3; ++t) {
            unsigned cA = (c_t[t] >= 1u) ? (q2[t].x & 0xffffu) : (unsigned)ZROW;
            unsigned cB = (c_t[t] >= 2u) ? (q2[t].x >> 16)     : (unsigned)ZROW;
            xA[t] = *reinterpret_cast<const short8*>(xb + (size_t)cA * 128 + m * 8);
            xB[t] = *reinterpret_cast<const short8*>(xb + (size_t)cB * 128 + m * 8);
        }
        xS = *reinterpret_cast<const short8*>(xb + (size_t)n * 128 + m * 8);
        const int ntS = ntype[n];

        #pragma unroll
        for (int t = 0; t < 3; ++t) build_tile(t, t, xA[t], xB[t]);
        *reinterpret_cast<uint4*>(sA + (3 * 32 + r) * 168 + m * 8) =
            *reinterpret_cast<const uint4*>(&xS);
        if (m < 4) {
            float g0 = (ntS == 2 * m) ? 1.f : 0.f;
            float g1 = (ntS == 2 * m + 1) ? 1.f : 0.f;
            reinterpret_cast<unsigned*>(sA)[(3 * 32 + r) * 84 + 64 + m] = pack2(g0, g1);
        }
    }

    __syncthreads();

    // ---- marathon 1: tiles 0..3, B types {0,1,2,6} ----
    f32x4 acc0 = {0.f, 0.f, 0.f, 0.f};
    f32x4 acc1 = {0.f, 0.f, 0.f, 0.f};
    const int ar = lane & 15;
    const int hi = (lane >> 4) << 3;

    #pragma unroll
    for (int i = 0; i < 4; ++i) {
        const int bt = (i == 3) ? 6 : i;
        short8 bv[5];
        #pragma unroll
        for (int kc = 0; kc < 5; ++kc)
            bv[kc] = *reinterpret_cast<const short8*>(
                wb + ((((bt * 5 + kc) * 8 + wid) << 6) + lane) * 8);
        #pragma unroll
        for (int kc = 0; kc < 5; ++kc) {
            short8 a0 = *reinterpret_cast<const short8*>(
                sA + (i * 32 + ar) * 168 + kc * 32 + hi);
            short8 a1 = *reinterpret_cast<const short8*>(
                sA + (i * 32 + 16 + ar) * 168 + kc * 32 + hi);
            acc0 = __builtin_amdgcn_mfma_f32_16x16x32_bf16(a0, bv[kc], acc0, 0, 0, 0);
            acc1 = __builtin_amdgcn_mfma_f32_16x16x32_bf16(a1, bv[kc], acc1, 0, 0, 0);
        }
    }

    __syncthreads();   // marathon-1 reads done before overwrite

    // ---- phase-2: issue all t3..5 loads up-front (MLP), then build ----
    {
        short8 xA2[3], xB2[3];
        #pragma unroll
        for (int t = 3; t < 6; ++t) {
            unsigned cA = (c_t[t] >= 1u) ? (q2[t].x & 0xffffu) : (unsigned)ZROW;
            unsigned cB = (c_t[t] >= 2u) ? (q2[t].x >> 16)     : (unsigned)ZROW;
            xA2[t - 3] = *reinterpret_cast<const short8*>(xb + (size_t)cA * 128 + m * 8);
            xB2[t - 3] = *reinterpret_cast<const short8*>(xb + (size_t)cB * 128 + m * 8);
        }
        #pragma unroll
        for (int t = 0; t < 3; ++t) build_tile(t + 3, t, xA2[t], xB2[t]);
    }

    __syncthreads();

    // ---- marathon 2: tiles 0..2, B types {3,4,5} ----
    #pragma unroll
    for (int i = 0; i < 3; ++i) {
        const int bt = 3 + i;
        short8 bv[5];
        #pragma unroll
        for (int kc = 0; kc < 5; ++kc)
            bv[kc] = *reinterpret_cast<const short8*>(
                wb + ((((bt * 5 + kc) * 8 + wid) << 6) + lane) * 8);
        #pragma unroll
        for (int kc = 0; kc < 5; ++kc) {
            short8 a0 = *reinterpret_cast<const short8*>(
                sA + (i * 32 + ar) * 168 + kc * 32 + hi);
            short8 a1 = *reinterpret_cast<const short8*>(
                sA + (i * 32 + 16 + ar) * 168 + kc * 32 + hi);
            acc0 = __builtin_amdgcn_mfma_f32_16x16x32_bf16(a0, bv[kc], acc0, 0, 0, 0);
            acc1 = __builtin_amdgcn_mfma_f32_16x16x32_bf16(a1, bv[kc], acc1, 0, 0, 0);
        }
    }

    // epilogue: C/D layout col = lane&15, row = (lane>>4)*4 + reg
    const int orow = n0 + ((lane >> 4) << 2);
    const int ocol = (wid << 4) + (lane & 15);
    #pragma unroll
    for (int rr = 0; rr < 4; ++rr) {
        out[(size_t)(orow + rr) * 128 + ocol]      = acc0[rr];
        out[(size_t)(orow + 16 + rr) * 128 + ocol] = acc1[rr];
    }
}

// ---------------- launch ----------------

extern "C" void kernel_launch(void* const* d_in, const int* in_sizes, int n_in,
                              void* d_out, int out_size, void* d_ws, size_t ws_size,
                              hipStream_t stream) {
    const float* x     = (const float*)d_in[0];
    const int*   eidx  = (const int*)d_in[1];
    const int*   etype = (const int*)d_in[2];
    const int*   ntype = (const int*)d_in[3];
    const float* W     = (const float*)d_in[4];
    float* out = (float*)d_out;

    // ws: xb (65537 rows) 16777472 | wb 286720 | seg32 1835008 | scol 11010048
    unsigned short* xb    = (unsigned short*)d_ws;
    unsigned short* wb    = (unsigned short*)((char*)d_ws + 16777472);
    unsigned*       seg32 = (unsigned*)((char*)d_ws + 17064192);
    unsigned short* scol  = (unsigned short*)((char*)d_ws + 18899200);

    hipMemsetAsync(seg32, 0, NSEG * sizeof(unsigned), stream);
    k_big <<<5888,         256, 0, stream>>>(x, eidx, etype, ntype, W, xb, wb, seg32, scol);
    k_main<<<N_NODES / 32, 512, 0, stream>>>(xb, ntype, seg32, scol, wb, out);
}